// Round 8
// baseline (829.775 us; speedup 1.0000x reference)
//
#include <hip/hip_runtime.h>
#include <cstdint>
#include <cstddef>

#define NH 16
#define ND 64
#define NK 256
#define NE 8
#define NV 196608
#define NBL 16384           // B*L = 4*4096
#define TOK 128             // tokens per block
#define MROW 17             // means LDS row stride in float4 (272B) - measured conflict-free (r5)
#define ACC_STRIDE 257

struct Primes { int p[NH]; };

// ---------------- K1: PQ assignment + EMA accumulation + normed_x ----------------
// 1024 threads (16 waves -> 4 waves/SIMD): c = tid&31 (8 clusters), r = tid>>5 (0..31; 4 tokens each)
__global__ __launch_bounds__(1024, 1) void k_pq(
    const float* __restrict__ x, const float* __restrict__ means,
    const float* __restrict__ lnxs, const float* __restrict__ lnxb,
    float* __restrict__ out, uint8_t* __restrict__ cids,
    float* __restrict__ gsum, int* __restrict__ gcnt)
{
  // floats: sm4 [256][17]f4 = 17408 | smsq4 [4][256] = 1024 | scnt 256 | sactive 256 | snact 1
  __shared__ __align__(16) float smem[18945];
  float4* sm4     = (float4*)smem;               // [256 cl][17] (slots 0..15 used)
  float*  smsq4   = smem + 17408;                // [4][256]
  int*    scnt    = (int*)(smem + 18432);        // [256]
  int*    sactive = (int*)(smem + 18688);        // [256]
  int*    snact   = (int*)(smem + 18944);
  float*  accum   = smem;                        // phase 2: [64 d][257] = 16448 f

  const int tid = threadIdx.x;
  const int c   = tid & 31;
  const int r   = tid >> 5;
  const int h   = blockIdx.y;
  const int g0  = blockIdx.x * TOK;

  // ---- stage means row-major (r5 pattern): thread = (cl = tid&255, quarter hf = tid>>8) ----
  {
    const int cl = tid & 255, hf = tid >> 8;
    const float4* src = (const float4*)(means + ((size_t)h * NK + cl) * ND + hf * 16);
    float mp = 0.f;
#pragma unroll
    for (int j = 0; j < 4; ++j) {
      float4 v = src[j];
      sm4[cl * MROW + hf * 4 + j] = v;
      mp += v.x * v.x + v.y * v.y + v.z * v.z + v.w * v.w;
    }
    smsq4[hf * NK + cl] = mp;
  }
  if (tid < NK) scnt[tid] = 0;
  if (tid == 0) *snact = 0;
  __syncthreads();

  // ---- distance GEMM: acc[j][i] = dot(x[token r*4+j], means[i*32+c]) ----
  float acc[4][8];
#pragma unroll
  for (int j = 0; j < 4; ++j)
#pragma unroll
    for (int i = 0; i < 8; ++i) acc[j][i] = 0.f;

  const float* xb = x + ((size_t)(g0 + r * 4) * NH + h) * ND;   // token stride 1024 f

  float4 cur[4];
#pragma unroll
  for (int j = 0; j < 4; ++j) cur[j] = *(const float4*)(xb + (size_t)j * (NH * ND));

#pragma unroll 2
  for (int dc = 0; dc < 16; ++dc) {
    float4 nxt[4];
    if (dc + 1 < 16) {
#pragma unroll
      for (int j = 0; j < 4; ++j)
        nxt[j] = *(const float4*)(xb + (size_t)j * (NH * ND) + (dc + 1) * 4);
    }
#pragma unroll
    for (int i = 0; i < 8; ++i) {
      float4 mv = sm4[(i * 32 + c) * MROW + dc];
#pragma unroll
      for (int j = 0; j < 4; ++j) {
        float a = acc[j][i];
        a = fmaf(cur[j].x, mv.x, a);
        a = fmaf(cur[j].y, mv.y, a);
        a = fmaf(cur[j].z, mv.z, a);
        a = fmaf(cur[j].w, mv.w, a);
        acc[j][i] = a;
      }
    }
    if (dc + 1 < 16) {
#pragma unroll
      for (int j = 0; j < 4; ++j) cur[j] = nxt[j];
    }
  }

  // ---- argmin (dist = msq - 2*dot; x_sq constant per token), tie-break smallest id ----
  int bk[4];
  {
    float bv[4]; int bi_[4];
#pragma unroll
    for (int j = 0; j < 4; ++j) { bv[j] = 3.4e38f; bi_[j] = 0; }
#pragma unroll
    for (int i = 0; i < 8; ++i) {
      const int cl = i * 32 + c;
      const float mq = (smsq4[cl] + smsq4[NK + cl]) + (smsq4[2 * NK + cl] + smsq4[3 * NK + cl]);
#pragma unroll
      for (int j = 0; j < 4; ++j) {
        float d = mq - 2.0f * acc[j][i];
        if (d < bv[j]) { bv[j] = d; bi_[j] = cl; }
      }
    }
#pragma unroll
    for (int j = 0; j < 4; ++j) {
      float v = bv[j]; int id = bi_[j];
#pragma unroll
      for (int m = 1; m < 32; m <<= 1) {               // stays within 32-lane halves
        float ov = __shfl_xor(v, m);
        int   oi = __shfl_xor(id, m);
        if (ov < v || (ov == v && oi < id)) { v = ov; id = oi; }
      }
      bk[j] = id;
    }
    if (c == 0) {
#pragma unroll
      for (int j = 0; j < 4; ++j) {
        cids[(size_t)(g0 + r * 4 + j) * NH + h] = (uint8_t)bk[j];
        atomicAdd(&scnt[bk[j]], 1);
      }
    }
  }

  __syncthreads();                                     // GEMM LDS reads done; scnt final

  // ---- zero accum + build active-cluster list ----
  for (int idx = tid; idx < ND * ACC_STRIDE; idx += 1024) accum[idx] = 0.f;
  if (tid < NK) {
    const int cnt = scnt[tid];
    if (cnt > 0) {
      int p = atomicAdd(snact, 1);
      sactive[p] = tid;
      atomicAdd(&gcnt[h * NK + tid], cnt);
    }
  }
  __syncthreads();

  // ---- EMA accumulate: lane (c,r): d = 2c,2c+1 for its 4 tokens ----
#pragma unroll
  for (int j = 0; j < 4; ++j) {
    float2 v = *(const float2*)(x + ((size_t)(g0 + r * 4 + j) * NH + h) * ND + c * 2);
    atomicAdd(&accum[(c * 2 + 0) * ACC_STRIDE + bk[j]], v.x);
    atomicAdd(&accum[(c * 2 + 1) * ACC_STRIDE + bk[j]], v.y);
  }

  // ---- normed_x -> out[0:56): thread = (token tl = tid>>3, octant q = tid&7) ----
  {
    const int tl = tid >> 3, q = tid & 7;
    const float* xt = x + ((size_t)(g0 + tl) * NH + h) * ND + q * 8;
    float4 v0 = *(const float4*)(xt);
    float4 v1 = *(const float4*)(xt + 4);
    float s  = v0.x + v0.y + v0.z + v0.w + v1.x + v1.y + v1.z + v1.w;
    float sq = v0.x * v0.x + v0.y * v0.y + v0.z * v0.z + v0.w * v0.w
             + v1.x * v1.x + v1.y * v1.y + v1.z * v1.z + v1.w * v1.w;
    s  += __shfl_xor(s, 1);  sq += __shfl_xor(sq, 1);
    s  += __shfl_xor(s, 2);  sq += __shfl_xor(sq, 2);
    s  += __shfl_xor(s, 4);  sq += __shfl_xor(sq, 4);
    float mu  = s * (1.f / 64.f);
    float var = sq * (1.f / 64.f) - mu * mu;
    float rs  = rsqrtf(var + 1e-5f);
    if (q < 7) {
      float4 s0 = *(const float4*)(lnxs + h * ND + q * 8);
      float4 s1 = *(const float4*)(lnxs + h * ND + q * 8 + 4);
      float4 b0 = *(const float4*)(lnxb + h * ND + q * 8);
      float4 b1 = *(const float4*)(lnxb + h * ND + q * 8 + 4);
      float4 o0, o1;
      o0.x = (v0.x - mu) * rs * s0.x + b0.x;
      o0.y = (v0.y - mu) * rs * s0.y + b0.y;
      o0.z = (v0.z - mu) * rs * s0.z + b0.z;
      o0.w = (v0.w - mu) * rs * s0.w + b0.w;
      o1.x = (v1.x - mu) * rs * s1.x + b1.x;
      o1.y = (v1.y - mu) * rs * s1.y + b1.y;
      o1.z = (v1.z - mu) * rs * s1.z + b1.z;
      o1.w = (v1.w - mu) * rs * s1.w + b1.w;
      float* orow = out + ((size_t)(g0 + tl) * NH + h) * ND + q * 8;
      *(float4*)(orow)     = o0;
      *(float4*)(orow + 4) = o1;
    }
  }
  __syncthreads();

  // ---- flush via active list: 16 groups of 64 d-lanes; gsum [h][k][d] coalesced ----
  {
    const int d = tid & 63, grp = tid >> 6;
    const int nact = *snact;
    for (int a = grp; a < nact; a += 16) {
      const int cl = sactive[a];
      atomicAdd(&gsum[(((size_t)h << 8) + cl) * ND + d], accum[d * ACC_STRIDE + cl]);
    }
  }
}

// ---------------- K2: bigram hash + embedding gather + LN_y -> out[56:64) ----------------
__global__ __launch_bounds__(256) void k_ngram(
    const uint8_t* __restrict__ cids, const float* __restrict__ embed,
    const float* __restrict__ lys, const float* __restrict__ lyb,
    float* __restrict__ out, Primes pr)
{
  const int i = blockIdx.x * 256 + threadIdx.x;  // 0 .. NBL*NH-1
  const int h = i & 15;
  const int g = i >> 4;
  const int l = g & 4095;                        // L = 4096

  int cid  = (int)cids[i];
  int prev = (l == 0) ? 0 : (int)cids[i - NH];
  int ng   = cid + (prev << 8);
  int hp1  = h + 1;
  int v    = ng * hp1 + hp1;
  const int p = pr.p[h];
  while (v >= p) v -= p;
  if (v >= NV) v -= NV;

  const float4* e4 = (const float4*)(embed + ((size_t)(v + NV * h)) * NE);
  float4 y0 = e4[0], y1 = e4[1];

  float s = ((y0.x + y0.y) + (y0.z + y0.w)) + ((y1.x + y1.y) + (y1.z + y1.w));
  float mu = s * 0.125f;
  float q = y0.x * y0.x + y0.y * y0.y + y0.z * y0.z + y0.w * y0.w
          + y1.x * y1.x + y1.y * y1.y + y1.z * y1.z + y1.w * y1.w;
  float var = q * 0.125f - mu * mu;
  float rs  = rsqrtf(var + 1e-5f);

  const float* sc = lys + h * NE;
  const float* bi = lyb + h * NE;
  float4 o0, o1;
  o0.x = (y0.x - mu) * rs * sc[0] + bi[0];
  o0.y = (y0.y - mu) * rs * sc[1] + bi[1];
  o0.z = (y0.z - mu) * rs * sc[2] + bi[2];
  o0.w = (y0.w - mu) * rs * sc[3] + bi[3];
  o1.x = (y1.x - mu) * rs * sc[4] + bi[4];
  o1.y = (y1.y - mu) * rs * sc[5] + bi[5];
  o1.z = (y1.z - mu) * rs * sc[6] + bi[6];
  o1.w = (y1.w - mu) * rs * sc[7] + bi[7];

  float4* orow = (float4*)(out + ((size_t)g * NH + h) * ND + 56);
  orow[0] = o0;
  orow[1] = o1;
}

// ---------------- K3: finalize new_means (gsum [h][k][d] = same flat order as means) ----------------
__global__ __launch_bounds__(256) void k_means(
    const float* __restrict__ means, const float* __restrict__ gsum,
    const int* __restrict__ gcnt, float* __restrict__ newm)
{
  const int i = blockIdx.x * 256 + threadIdx.x;  // flat [h][k][d]
  float cnt = (float)gcnt[i >> 6];
  float mx  = gsum[i] / (1e-6f + cnt);
  newm[i] = 0.001f * mx + 0.999f * means[i];
}

extern "C" void kernel_launch(void* const* d_in, const int* in_sizes, int n_in,
                              void* d_out, int out_size, void* d_ws, size_t ws_size,
                              hipStream_t stream)
{
  const float* x     = (const float*)d_in[0];
  const float* means = (const float*)d_in[1];
  const float* embed = (const float*)d_in[2];
  const float* lnxs  = (const float*)d_in[3];
  const float* lnxb  = (const float*)d_in[4];
  const float* lys   = (const float*)d_in[5];
  const float* lyb   = (const float*)d_in[6];

  float* out  = (float*)d_out;
  float* newm = out + (size_t)NBL * NH * ND;

  float*   gsum = (float*)d_ws;
  int*     gcnt = (int*)((char*)d_ws + (size_t)NH * NK * ND * 4);
  uint8_t* cids = (uint8_t*)((char*)d_ws + (size_t)NH * NK * ND * 4 + (size_t)NH * NK * 4);

  hipMemsetAsync(d_ws, 0, (size_t)NH * NK * ND * 4 + (size_t)NH * NK * 4, stream);

  Primes pr;
  {
    int n = NV, c = 0;
    while (c < NH) {
      ++n;
      bool isp = true;
      for (int q = 2; (long long)q * q <= n; ++q)
        if (n % q == 0) { isp = false; break; }
      if (isp) pr.p[c++] = n;
    }
  }

  dim3 g1(NBL / TOK, NH);
  k_pq<<<g1, 1024, 0, stream>>>(x, means, lnxs, lnxb, out, cids, gsum, gcnt);
  k_ngram<<<(NBL * NH) / 256, 256, 0, stream>>>(cids, embed, lys, lyb, out, pr);
  k_means<<<(NH * NK * ND) / 256, 256, 0, stream>>>(means, gsum, gcnt, newm);
}

// Round 9
// 421.605 us; speedup vs baseline: 1.9681x; 1.9681x over previous
//
#include <hip/hip_runtime.h>
#include <cstdint>
#include <cstddef>

#define NH 16
#define ND 64
#define NK 256
#define NE 8
#define NV 196608
#define NBL 16384           // B*L = 4*4096
#define TOK 512             // tokens per block (1 per thread)
#define MS 68               // means LDS row stride in floats (272B, f4-aligned, measured conflict-free)
#define ACC_STRIDE 257

struct Primes { int p[NH]; };

// ---------------- K1: PQ assignment + EMA accumulation + normed_x ----------------
// 512 threads, 1 token each. Means in LDS; inner loop reads means rows WAVE-UNIFORM
// (hardware broadcast, no lane-varying LDS traffic). x stays in registers throughout.
// (512,2): 2 blocks/CU (74KB LDS) -> 16 waves/CU = 4 waves/SIMD, 128-VGPR cap.
__global__ __launch_bounds__(512, 2) void k_pq(
    const float* __restrict__ x, const float* __restrict__ means,
    const float* __restrict__ lnxs, const float* __restrict__ lnxb,
    float* __restrict__ out, uint8_t* __restrict__ cids,
    float* __restrict__ gsum, int* __restrict__ gcnt)
{
  // floats: sm [256][68]=17408 | smsq2 [2][256]=512 | scnt 256 | sactive 256 | snact 1 | lnsc 64 | lnbi 64
  __shared__ __align__(16) float smem[18561];
  float*  sm      = smem;                        // [256 cl][68] (cols 0..63 used)
  float*  smsq2   = smem + 17408;                // [2][256]
  int*    scnt    = (int*)(smem + 17920);        // [256]
  int*    sactive = (int*)(smem + 18176);        // [256]
  int*    snact   = (int*)(smem + 18432);
  float*  lnsc    = smem + 18433;                // [64]
  float*  lnbi    = smem + 18497;                // [64]
  float*  accum   = smem;                        // phase 2 overlay: [64 d][257] = 16448 f

  const int tid = threadIdx.x;
  const int h   = blockIdx.y;
  const int g0  = blockIdx.x * TOK;
  const int g   = g0 + tid;

  // ---- stage means (half-row per thread, coalesced 128B) ----
  {
    const int cl = tid >> 1, hf = tid & 1;
    const float4* src = (const float4*)(means + ((size_t)h * NK + cl) * ND + hf * 32);
    float4* dst = (float4*)(sm + cl * MS + hf * 32);
    float mp = 0.f;
#pragma unroll
    for (int j = 0; j < 8; ++j) {
      float4 v = src[j];
      dst[j] = v;
      mp += v.x * v.x + v.y * v.y + v.z * v.z + v.w * v.w;
    }
    smsq2[hf * NK + cl] = mp;
  }
  if (tid < ND) { lnsc[tid] = lnxs[h * ND + tid]; lnbi[tid] = lnxb[h * ND + tid]; }
  if (tid < NK) scnt[tid] = 0;
  if (tid == 0) *snact = 0;
  __syncthreads();
  if (tid < NK) smsq2[tid] += smsq2[NK + tid];   // combine halves
  __syncthreads();

  // ---- load this thread's token into registers ----
  const float4* xg = (const float4*)(x + ((size_t)g * NH + h) * ND);
  float4 xr[16];
  float xsum = 0.f, xsq = 0.f;
#pragma unroll
  for (int i = 0; i < 16; ++i) {
    float4 v = xg[i];
    xr[i] = v;
    xsum += v.x + v.y + v.z + v.w;
    xsq  += v.x * v.x + v.y * v.y + v.z * v.z + v.w * v.w;
  }

  // ---- argmin over 256 clusters: wave-uniform means reads (broadcast) ----
  float best = 3.4e38f;
  int bk = 0;
#pragma unroll 2
  for (int k = 0; k < NK; ++k) {
    const float4* m4 = (const float4*)(sm + k * MS);
    float ax = 0.f, ay = 0.f, az = 0.f, aw = 0.f;
#pragma unroll
    for (int i = 0; i < 16; ++i) {
      float4 m = m4[i];
      ax = fmaf(xr[i].x, m.x, ax);
      ay = fmaf(xr[i].y, m.y, ay);
      az = fmaf(xr[i].z, m.z, az);
      aw = fmaf(xr[i].w, m.w, aw);
    }
    float dot  = (ax + ay) + (az + aw);
    float dist = smsq2[k] - 2.0f * dot;          // x_sq dropped (argmin-invariant)
    if (dist < best) { best = dist; bk = k; }    // strict < => first-index tie-break
  }
  cids[(size_t)g * NH + h] = (uint8_t)bk;
  atomicAdd(&scnt[bk], 1);

  __syncthreads();                               // sm reads done; scnt final

  // ---- zero accum (overlays sm) + build active-cluster list ----
  for (int idx = tid; idx < ND * ACC_STRIDE; idx += 512) accum[idx] = 0.f;
  if (tid < NK) {
    const int cnt = scnt[tid];
    if (cnt > 0) {
      int p = atomicAdd(snact, 1);
      sactive[p] = tid;
      atomicAdd(&gcnt[h * NK + tid], cnt);
    }
  }
  __syncthreads();

  // ---- EMA accumulate from registers: bank = (d + bk) % 32 -> scattered ----
#pragma unroll
  for (int i = 0; i < 16; ++i) {
    atomicAdd(&accum[(4 * i + 0) * ACC_STRIDE + bk], xr[i].x);
    atomicAdd(&accum[(4 * i + 1) * ACC_STRIDE + bk], xr[i].y);
    atomicAdd(&accum[(4 * i + 2) * ACC_STRIDE + bk], xr[i].z);
    atomicAdd(&accum[(4 * i + 3) * ACC_STRIDE + bk], xr[i].w);
  }

  // ---- normed_x from registers -> out[0:56) ----
  {
    float mu  = xsum * (1.f / 64.f);
    float var = xsq * (1.f / 64.f) - mu * mu;
    float rs  = rsqrtf(var + 1e-5f);
    float* orow = out + ((size_t)g * NH + h) * ND;
#pragma unroll
    for (int i = 0; i < 14; ++i) {               // 14*4 = 56 features
      float4 v = xr[i];
      float4 o;
      o.x = (v.x - mu) * rs * lnsc[4 * i + 0] + lnbi[4 * i + 0];
      o.y = (v.y - mu) * rs * lnsc[4 * i + 1] + lnbi[4 * i + 1];
      o.z = (v.z - mu) * rs * lnsc[4 * i + 2] + lnbi[4 * i + 2];
      o.w = (v.w - mu) * rs * lnsc[4 * i + 3] + lnbi[4 * i + 3];
      ((float4*)orow)[i] = o;
    }
  }
  __syncthreads();

  // ---- flush via active list: 8 groups of 64 d-lanes; gsum [h][k][d] coalesced ----
  {
    const int d = tid & 63, grp = tid >> 6;
    const int nact = *snact;
    for (int a = grp; a < nact; a += 8) {
      const int cl = sactive[a];
      atomicAdd(&gsum[(((size_t)h << 8) + cl) * ND + d], accum[d * ACC_STRIDE + cl]);
    }
  }
}

// ---------------- K2: bigram hash + embedding gather + LN_y -> out[56:64) ----------------
__global__ __launch_bounds__(256) void k_ngram(
    const uint8_t* __restrict__ cids, const float* __restrict__ embed,
    const float* __restrict__ lys, const float* __restrict__ lyb,
    float* __restrict__ out, Primes pr)
{
  const int i = blockIdx.x * 256 + threadIdx.x;  // 0 .. NBL*NH-1
  const int h = i & 15;
  const int g = i >> 4;
  const int l = g & 4095;                        // L = 4096

  int cid  = (int)cids[i];
  int prev = (l == 0) ? 0 : (int)cids[i - NH];
  int ng   = cid + (prev << 8);
  int hp1  = h + 1;
  int v    = ng * hp1 + hp1;
  const int p = pr.p[h];
  while (v >= p) v -= p;
  if (v >= NV) v -= NV;

  const float4* e4 = (const float4*)(embed + ((size_t)(v + NV * h)) * NE);
  float4 y0 = e4[0], y1 = e4[1];

  float s = ((y0.x + y0.y) + (y0.z + y0.w)) + ((y1.x + y1.y) + (y1.z + y1.w));
  float mu = s * 0.125f;
  float q = y0.x * y0.x + y0.y * y0.y + y0.z * y0.z + y0.w * y0.w
          + y1.x * y1.x + y1.y * y1.y + y1.z * y1.z + y1.w * y1.w;
  float var = q * 0.125f - mu * mu;
  float rs  = rsqrtf(var + 1e-5f);

  const float* sc = lys + h * NE;
  const float* bi = lyb + h * NE;
  float4 o0, o1;
  o0.x = (y0.x - mu) * rs * sc[0] + bi[0];
  o0.y = (y0.y - mu) * rs * sc[1] + bi[1];
  o0.z = (y0.z - mu) * rs * sc[2] + bi[2];
  o0.w = (y0.w - mu) * rs * sc[3] + bi[3];
  o1.x = (y1.x - mu) * rs * sc[4] + bi[4];
  o1.y = (y1.y - mu) * rs * sc[5] + bi[5];
  o1.z = (y1.z - mu) * rs * sc[6] + bi[6];
  o1.w = (y1.w - mu) * rs * sc[7] + bi[7];

  float4* orow = (float4*)(out + ((size_t)g * NH + h) * ND + 56);
  orow[0] = o0;
  orow[1] = o1;
}

// ---------------- K3: finalize new_means (gsum [h][k][d] = same flat order as means) ----------------
__global__ __launch_bounds__(256) void k_means(
    const float* __restrict__ means, const float* __restrict__ gsum,
    const int* __restrict__ gcnt, float* __restrict__ newm)
{
  const int i = blockIdx.x * 256 + threadIdx.x;  // flat [h][k][d]
  float cnt = (float)gcnt[i >> 6];
  float mx  = gsum[i] / (1e-6f + cnt);
  newm[i] = 0.001f * mx + 0.999f * means[i];
}

extern "C" void kernel_launch(void* const* d_in, const int* in_sizes, int n_in,
                              void* d_out, int out_size, void* d_ws, size_t ws_size,
                              hipStream_t stream)
{
  const float* x     = (const float*)d_in[0];
  const float* means = (const float*)d_in[1];
  const float* embed = (const float*)d_in[2];
  const float* lnxs  = (const float*)d_in[3];
  const float* lnxb  = (const float*)d_in[4];
  const float* lys   = (const float*)d_in[5];
  const float* lyb   = (const float*)d_in[6];

  float* out  = (float*)d_out;
  float* newm = out + (size_t)NBL * NH * ND;

  float*   gsum = (float*)d_ws;
  int*     gcnt = (int*)((char*)d_ws + (size_t)NH * NK * ND * 4);
  uint8_t* cids = (uint8_t*)((char*)d_ws + (size_t)NH * NK * ND * 4 + (size_t)NH * NK * 4);

  hipMemsetAsync(d_ws, 0, (size_t)NH * NK * ND * 4 + (size_t)NH * NK * 4, stream);

  Primes pr;
  {
    int n = NV, c = 0;
    while (c < NH) {
      ++n;
      bool isp = true;
      for (int q = 2; (long long)q * q <= n; ++q)
        if (n % q == 0) { isp = false; break; }
      if (isp) pr.p[c++] = n;
    }
  }

  dim3 g1(NBL / TOK, NH);                        // 32 x 16 = 512 blocks = 2/CU exactly
  k_pq<<<g1, 512, 0, stream>>>(x, means, lnxs, lnxb, out, cids, gsum, gcnt);
  k_ngram<<<(NBL * NH) / 256, 256, 0, stream>>>(cids, embed, lys, lyb, out, pr);
  k_means<<<(NH * NK * ND) / 256, 256, 0, stream>>>(means, gsum, gcnt, newm);
}